// Round 9
// baseline (128.384 us; speedup 1.0000x reference)
//
#include <hip/hip_runtime.h>
#include <math.h>

#define NN 768
#define EN 64
#define EE 16
#define FF 64
#define ROWS 1536   // B*N, B=2

typedef float vfloat4 __attribute__((ext_vector_type(4)));

// ---------------------------------------------------------------------------
// Kernel 1: 4 rows per 256-thread block; wave w owns row bid*4+w.
//  h[row,f] = nodes[row,:] @ W_node[:,f];  r[row] = h[row,:]·a_row
//  block 0 / wave 0 additionally computes we[k] = W_edge[k,:]·a_edge, S_c.
// ---------------------------------------------------------------------------
__global__ __launch_bounds__(256) void node_proj(const float* __restrict__ nodes,
                                                 const float* __restrict__ W_node,
                                                 const float* __restrict__ W_edge,
                                                 const float* __restrict__ a_w,
                                                 float* __restrict__ h,
                                                 float* __restrict__ r,
                                                 float* __restrict__ we) {
    const int t = threadIdx.x;
    const int w = t >> 6;             // wave id (0..3)
    const int lane = t & 63;
    const int row = blockIdx.x * 4 + w;

    const float nv = nodes[(size_t)row * EN + lane];   // lane k holds nodes[row,k]
    float acc = 0.f;
    #pragma unroll
    for (int k = 0; k < EN; ++k)
        acc = fmaf(__shfl(nv, k), W_node[k * FF + lane], acc);
    h[(size_t)row * FF + lane] = acc;
    float rv = acc * a_w[lane];
    #pragma unroll
    for (int off = 32; off; off >>= 1) rv += __shfl_xor(rv, off);
    if (lane == 0) r[row] = rv;

    if (blockIdx.x == 0 && w == 0) {  // fused prep: we[0:16], we[16]=S_c
        if (lane < EE) {
            float s = 0.f;
            #pragma unroll
            for (int f = 0; f < FF; ++f) s = fmaf(W_edge[lane * FF + f], a_w[FF + f], s);
            we[lane] = s;
        } else if (lane == EE) {
            float s = 0.f;
            #pragma unroll
            for (int f = 0; f < FF; ++f) s += a_w[2 * FF + f];
            we[EE] = s;
        }
    }
}

// ---------------------------------------------------------------------------
// Kernel 2: main. One block per ROW PAIR (2b, 2b+1), 512 threads (8 waves).
//  waves 0-3 handle row rr=0, waves 4-7 row rr=1 for the edge stream;
//  phase 4 shares each h load between both rows (halves L2 traffic).
// ---------------------------------------------------------------------------
__global__ __launch_bounds__(512) void gat_main(const float* __restrict__ edges,
                                                const int* __restrict__ mask,
                                                const float* __restrict__ h,
                                                const float* __restrict__ r,
                                                const float* __restrict__ we_g,
                                                float* __restrict__ out) {
    const int bid = blockIdx.x;          // row pair
    const int t = threadIdx.x;
    const int rr = t >> 8;               // which row of the pair
    const int tt = t & 255;              // lane within the row team
    const int row = 2 * bid + rr;
    const int bN = (row >= NN) ? NN : 0; // column base of this batch

    __shared__ __align__(16) float we_l[EE];
    __shared__ float base_l[2][EN];      // r_i + h[row,q]*S_c  (q = j/12)
    __shared__ float s_aw[2][NN];
    __shared__ float redM[8], redS[8];
    __shared__ float redP[8][2][FF];

    if (t < EE) we_l[t] = we_g[t];
    if (t < 128) {                       // per-pair additive table
        const int pr = t >> 6, q = t & 63;
        const int prow = 2 * bid + pr;
        base_l[pr][q] = r[prow] + h[(size_t)prow * FF + q] * we_g[EE];
    }
    const float mf = (mask[row] != 0) ? 1.f : 0.f;
    __syncthreads();

    // ---- phase 2: scores — nontemporal, fully-pipelined float4 stream ----
    const vfloat4* erow = (const vfloat4*)(edges + (size_t)row * (NN * EE));
    const int g = tt & 3;
    const int jbase = tt >> 2;
    const vfloat4 wev = ((const vfloat4*)we_l)[g];

    vfloat4 ev[12];
    #pragma unroll
    for (int k = 0; k < 12; ++k)
        ev[k] = __builtin_nontemporal_load(&erow[k * 256 + tt]);

    float mx = -INFINITY;
    #pragma unroll
    for (int k = 0; k < 12; ++k) {
        const vfloat4 e = ev[k];
        float d = e.x * wev.x + e.y * wev.y + e.z * wev.z + e.w * wev.w;
        d += __shfl_xor(d, 1);
        d += __shfl_xor(d, 2);           // 4-lane group now holds full 16-dot
        const int j = k * 64 + jbase;
        float s = base_l[rr][j / 12] + d;
        float aw = (s > 0.f) ? s : 0.2f * s;
        aw *= mf;
        if (g == 0) s_aw[rr][j] = aw;
        mx = fmaxf(mx, aw);
    }
    #pragma unroll
    for (int off = 32; off; off >>= 1) mx = fmaxf(mx, __shfl_xor(mx, off));
    if ((t & 63) == 0) redM[t >> 6] = mx;
    __syncthreads();
    {
        const int b = rr * 4;
        mx = fmaxf(fmaxf(redM[b], redM[b + 1]), fmaxf(redM[b + 2], redM[b + 3]));
    }

    // ---- phase 3: exp + sum; numerator gated by adj = (aw > 0) ----
    float sum = 0.f;
    #pragma unroll
    for (int jj = 0; jj < 3; ++jj) {
        const int j = jj * 256 + tt;
        const float aw = s_aw[rr][j];
        const float ex = __expf(aw - mx);
        sum += ex;
        s_aw[rr][j] = (aw > 0.f) ? ex : 0.f;
    }
    #pragma unroll
    for (int off = 32; off; off >>= 1) sum += __shfl_xor(sum, off);
    if ((t & 63) == 0) redS[t >> 6] = sum;
    __syncthreads();

    // ---- phase 4: out[row,f] = inv * Σ_j s_aw[j] * h[bN+j,f], h shared ----
    const int f = t & 63;
    const int ch = t >> 6;               // wave id = j-chunk (8 × 96)
    const float* hb = h + (size_t)bN * FF;
    float acc0 = 0.f, acc1 = 0.f;
    const int j0 = ch * 96;
    #pragma unroll 4
    for (int j = j0; j < j0 + 96; ++j) {
        const float hv = hb[(size_t)j * FF + f];
        acc0 = fmaf(s_aw[0][j], hv, acc0);
        acc1 = fmaf(s_aw[1][j], hv, acc1);
    }
    redP[ch][0][f] = acc0;
    redP[ch][1][f] = acc1;
    __syncthreads();
    if (t < 128) {
        const int pr = t >> 6, q = t & 63;
        const float inv = 1.f / (redS[pr * 4] + redS[pr * 4 + 1] +
                                 redS[pr * 4 + 2] + redS[pr * 4 + 3]);
        float o = 0.f;
        #pragma unroll
        for (int c = 0; c < 8; ++c) o += redP[c][pr][q];
        out[(size_t)(2 * bid + pr) * FF + q] = o * inv;
    }
}

// ---------------------------------------------------------------------------
extern "C" void kernel_launch(void* const* d_in, const int* in_sizes, int n_in,
                              void* d_out, int out_size, void* d_ws, size_t ws_size,
                              hipStream_t stream) {
    const float* nodes  = (const float*)d_in[0];   // (B,N,EN)
    const float* edges  = (const float*)d_in[1];   // (B,N,N,EE)
    const int*   nmask  = (const int*)d_in[2];     // (B,N) bool->int32
    const float* W_node = (const float*)d_in[3];   // (EN,F)
    const float* W_edge = (const float*)d_in[4];   // (EE,F)
    const float* a_w    = (const float*)d_in[5];   // (3F,1)
    float* out = (float*)d_out;

    float* ws = (float*)d_ws;
    float* h  = ws;                       // ROWS*FF
    float* r  = h + (size_t)ROWS * FF;    // ROWS
    float* we = r + ROWS;                 // EE+1

    node_proj<<<ROWS / 4, 256, 0, stream>>>(nodes, W_node, W_edge, a_w, h, r, we);
    gat_main<<<ROWS / 2, 512, 0, stream>>>(edges, nmask, h, r, we, out);
}

// Round 10
// 123.498 us; speedup vs baseline: 1.0396x; 1.0396x over previous
//
#include <hip/hip_runtime.h>
#include <math.h>

#define NN 768
#define EN 64
#define EE 16
#define FF 64
#define ROWS 1536   // B*N, B=2

// ---------------------------------------------------------------------------
// Kernel 1: per row: h[row,f] = nodes[row,:] @ W_node[:,f];  r[row] = h·a_row
// block 0 additionally computes we[k] = W_edge[k,:]·a_edge and S_c = Σ a_col.
// ---------------------------------------------------------------------------
__global__ __launch_bounds__(64) void node_proj(const float* __restrict__ nodes,
                                                const float* __restrict__ W_node,
                                                const float* __restrict__ W_edge,
                                                const float* __restrict__ a_w,
                                                float* __restrict__ h,
                                                float* __restrict__ r,
                                                float* __restrict__ we) {
    const int row = blockIdx.x;
    const int t = threadIdx.x;
    __shared__ float nd[EN];
    nd[t] = nodes[(size_t)row * EN + t];
    __syncthreads();
    float acc = 0.f;
    #pragma unroll
    for (int k = 0; k < EN; ++k) acc = fmaf(nd[k], W_node[k * FF + t], acc);
    h[(size_t)row * FF + t] = acc;
    float rv = acc * a_w[t];
    #pragma unroll
    for (int off = 32; off; off >>= 1) rv += __shfl_xor(rv, off);
    if (t == 0) r[row] = rv;

    if (row == 0) {                 // fused prep: we[0:16], we[16]=S_c
        if (t < EE) {
            float s = 0.f;
            #pragma unroll
            for (int f = 0; f < FF; ++f) s = fmaf(W_edge[t * FF + f], a_w[FF + f], s);
            we[t] = s;
        } else if (t == EE) {
            float s = 0.f;
            #pragma unroll
            for (int f = 0; f < FF; ++f) s += a_w[2 * FF + f];
            we[EE] = s;
        }
    }
}

// ---------------------------------------------------------------------------
// Kernel 2: main. One block per ROW PAIR (2b, 2b+1), 512 threads (8 waves).
//  waves 0-3 handle row rr=0, waves 4-7 row rr=1 for the edge stream;
//  phase 4 shares each h load between both rows (halves L2 traffic).
// ---------------------------------------------------------------------------
__global__ __launch_bounds__(512) void gat_main(const float* __restrict__ edges,
                                                const int* __restrict__ mask,
                                                const float* __restrict__ h,
                                                const float* __restrict__ r,
                                                const float* __restrict__ we_g,
                                                float* __restrict__ out) {
    const int bid = blockIdx.x;          // row pair
    const int t = threadIdx.x;
    const int rr = t >> 8;               // which row of the pair
    const int tt = t & 255;              // lane within the row team
    const int row = 2 * bid + rr;
    const int bN = (row >= NN) ? NN : 0; // column base of this batch

    __shared__ __align__(16) float we_l[EE];
    __shared__ float base_l[2][EN];      // r_i + h[row,q]*S_c  (q = j/12)
    __shared__ float s_aw[2][NN];
    __shared__ float redM[8], redS[8];
    __shared__ float redP[8][2][FF];

    if (t < EE) we_l[t] = we_g[t];
    if (t < 128) {                       // per-pair additive table
        const int pr = t >> 6, q = t & 63;
        const int prow = 2 * bid + pr;
        base_l[pr][q] = r[prow] + h[(size_t)prow * FF + q] * we_g[EE];
    }
    const float mf = (mask[row] != 0) ? 1.f : 0.f;
    __syncthreads();

    // ---- phase 2: scores — coalesced float4 stream of this row's edges ----
    const float4* erow = (const float4*)(edges + (size_t)row * (NN * EE));
    const int g = tt & 3;
    const int jbase = tt >> 2;
    const float4 wev = ((const float4*)we_l)[g];
    float mx = -INFINITY;
    #pragma unroll 4
    for (int k = 0; k < 12; ++k) {
        float4 ev = erow[k * 256 + tt];
        float d = ev.x * wev.x + ev.y * wev.y + ev.z * wev.z + ev.w * wev.w;
        d += __shfl_xor(d, 1);
        d += __shfl_xor(d, 2);           // 4-lane group now holds full 16-dot
        const int j = k * 64 + jbase;
        float s = base_l[rr][j / 12] + d;
        float aw = (s > 0.f) ? s : 0.2f * s;
        aw *= mf;
        if (g == 0) s_aw[rr][j] = aw;
        mx = fmaxf(mx, aw);
    }
    #pragma unroll
    for (int off = 32; off; off >>= 1) mx = fmaxf(mx, __shfl_xor(mx, off));
    if ((t & 63) == 0) redM[t >> 6] = mx;
    __syncthreads();
    {
        const int b = rr * 4;
        mx = fmaxf(fmaxf(redM[b], redM[b + 1]), fmaxf(redM[b + 2], redM[b + 3]));
    }

    // ---- phase 3: exp + sum; numerator gated by adj = (aw > 0) ----
    float sum = 0.f;
    #pragma unroll
    for (int jj = 0; jj < 3; ++jj) {
        const int j = jj * 256 + tt;
        const float aw = s_aw[rr][j];
        const float ex = __expf(aw - mx);
        sum += ex;
        s_aw[rr][j] = (aw > 0.f) ? ex : 0.f;
    }
    #pragma unroll
    for (int off = 32; off; off >>= 1) sum += __shfl_xor(sum, off);
    if ((t & 63) == 0) redS[t >> 6] = sum;
    __syncthreads();

    // ---- phase 4: out[row,f] = inv * Σ_j s_aw[j] * h[bN+j,f], h shared ----
    const int f = t & 63;
    const int ch = t >> 6;               // wave id = j-chunk (8 × 96)
    const float* hb = h + (size_t)bN * FF;
    float acc0 = 0.f, acc1 = 0.f;
    const int j0 = ch * 96;
    #pragma unroll 4
    for (int j = j0; j < j0 + 96; ++j) {
        const float hv = hb[(size_t)j * FF + f];
        acc0 = fmaf(s_aw[0][j], hv, acc0);
        acc1 = fmaf(s_aw[1][j], hv, acc1);
    }
    redP[ch][0][f] = acc0;
    redP[ch][1][f] = acc1;
    __syncthreads();
    if (t < 128) {
        const int pr = t >> 6, q = t & 63;
        const float inv = 1.f / (redS[pr * 4] + redS[pr * 4 + 1] +
                                 redS[pr * 4 + 2] + redS[pr * 4 + 3]);
        float o = 0.f;
        #pragma unroll
        for (int c = 0; c < 8; ++c) o += redP[c][pr][q];
        out[(size_t)(2 * bid + pr) * FF + q] = o * inv;
    }
}

// ---------------------------------------------------------------------------
extern "C" void kernel_launch(void* const* d_in, const int* in_sizes, int n_in,
                              void* d_out, int out_size, void* d_ws, size_t ws_size,
                              hipStream_t stream) {
    const float* nodes  = (const float*)d_in[0];   // (B,N,EN)
    const float* edges  = (const float*)d_in[1];   // (B,N,N,EE)
    const int*   nmask  = (const int*)d_in[2];     // (B,N) bool->int32
    const float* W_node = (const float*)d_in[3];   // (EN,F)
    const float* W_edge = (const float*)d_in[4];   // (EE,F)
    const float* a_w    = (const float*)d_in[5];   // (3F,1)
    float* out = (float*)d_out;

    float* ws = (float*)d_ws;
    float* h  = ws;                       // ROWS*FF
    float* r  = h + (size_t)ROWS * FF;    // ROWS
    float* we = r + ROWS;                 // EE+1

    node_proj<<<ROWS, 64, 0, stream>>>(nodes, W_node, W_edge, a_w, h, r, we);
    gat_main<<<ROWS / 2, 512, 0, stream>>>(edges, nmask, h, r, we, out);
}